// Round 23
// baseline (65.435 us; speedup 1.0000x reference)
//
#include <hip/hip_runtime.h>
#include <math.h>

// PseudoGroupContrast — SPLIT v4: phase-separated, shuffle-free rows pass.
//
//   R20-22 triangulation: 44-50 µs regardless of lanes/row, shuffle depth,
//   contiguity. Hypothesis: dependent ds_bpermute chains interleaved with
//   loads stall waves (VALUBusy 14%, warm==cold). v4 makes the load phase
//   EXACTLY copy-like: no cross-lane ops, independent iterations.
//
//   pgc_rows: per 64-row tile (block 512):
//     A: f = i*512+tid (wave-contiguous); load act4/ema4[f]; 3 dots -> LDS
//        partials [row][slot]. No shuffles, no deps between i.
//     B: thread r<64 sums 32 partials/row -> inva/inve/gs/def2 + meta
//        (plab/mask loads here too).
//     C: re-read act fragment-wise from L2-hot global (coalesced), pk8,
//        coalesced afb stores.
//   pgc_mm: R16/R20 proven qt-in-LDS MFMA loop (~9 µs with preps).
//   prep/prepQ/finish unchanged.

#define D       128
#define NQ      375
#define QS      125
#define INV126  (1.0f/126.0f)
#define QT_BYTES 49152
#define TR      64            // rows per tile in pgc_rows

typedef __attribute__((ext_vector_type(4))) float f32x4;

#if defined(__has_builtin)
#if __has_builtin(__builtin_amdgcn_cvt_pk_fp8_f32)
#define HAVE_CVT_FP8 1
#endif
#endif

#ifndef HAVE_CVT_FP8
static __device__ __forceinline__ unsigned f2e4m3_sw(float x) {
    unsigned u = __float_as_uint(x);
    unsigned s = (u >> 24) & 0x80;
    int e = (int)((u >> 23) & 0xFF);
    unsigned m = u & 0x7FFFFF;
    if (e == 0) return s;
    int te = e - 120;
    unsigned val;
    if (te >= 1) {
        unsigned keep = m >> 20;
        unsigned rest = m & 0xFFFFF;
        keep += (rest > 0x80000) || (rest == 0x80000 && (keep & 1));
        if (keep == 8) { keep = 0; te += 1; }
        val = (te >= 16) ? 0x7E : ((unsigned)(te << 3) | keep);
    } else {
        unsigned full = m | 0x800000;
        int sh = 21 - te;
        if (sh > 31) val = 0;
        else {
            unsigned keep = full >> sh;
            unsigned rem = full & ((1u << sh) - 1);
            unsigned half = 1u << (sh - 1);
            keep += (rem > half) || (rem == half && (keep & 1));
            val = keep;
        }
    }
    return s | val;
}
#endif

static __device__ __forceinline__ unsigned pk4(float4 v) {
#ifdef HAVE_CVT_FP8
    int r = __builtin_amdgcn_cvt_pk_fp8_f32(v.x, v.y, 0, false);
    r = __builtin_amdgcn_cvt_pk_fp8_f32(v.z, v.w, r, true);
    return (unsigned)r;
#else
    return f2e4m3_sw(v.x) | (f2e4m3_sw(v.y) << 8)
         | (f2e4m3_sw(v.z) << 16) | (f2e4m3_sw(v.w) << 24);
#endif
}

static __device__ __forceinline__ unsigned char pk1(float x) {
#ifdef HAVE_CVT_FP8
    return (unsigned char)(__builtin_amdgcn_cvt_pk_fp8_f32(x, x, 0, false) & 0xff);
#else
    return (unsigned char)f2e4m3_sw(x);
#endif
}

static __device__ __forceinline__ void glds16(const void* g, void* l) {
    __builtin_amdgcn_global_load_lds(
        (const __attribute__((address_space(1))) void*)g,
        (__attribute__((address_space(3))) void*)l, 16, 0, 0);
}

// ---- prep: queue -> fp8, fragment-tiled (rows >= 375 zeroed) ----
__global__ void pgc_prep(const float* __restrict__ queue,
                         unsigned long long* __restrict__ qt)
{
    int u = blockIdx.x * 256 + threadIdx.x;      // 0..6143
    if (u >= 6144) return;
    int l = u & 63, ks = (u >> 6) & 3, nt = u >> 8;
    int row = nt * 16 + (l & 15);
    int k0 = (l >> 4) * 32 + ks * 8;
    float4 a = make_float4(0.f, 0.f, 0.f, 0.f);
    float4 b = make_float4(0.f, 0.f, 0.f, 0.f);
    if (row < NQ) {
        const float* p = queue + row * D + k0;
        a = *(const float4*)p;
        b = *(const float4*)(p + 4);
    }
    unsigned lo = pk4(a), hi = pk4(b);
    qt[u] = ((unsigned long long)hi << 32) | (unsigned long long)lo;
}

// ---- prepQ: class sums into pad rows 375..377 (tile 23, lr=7..9) ----
__global__ void pgc_prep_qsum(const float* __restrict__ queue,
                              unsigned char* __restrict__ qtb)
{
    int c = blockIdx.x;          // 0..2
    int d = threadIdx.x;         // 0..127
    float s = 0.f;
    const float* p = queue + (long)c * QS * D + d;
    for (int r = 0; r < QS; ++r) s += p[r * D];
    int lg = d >> 5, ks = (d >> 3) & 3, j = d & 7;
    int u = 23 * 256 + ks * 64 + lg * 16 + 7 + c;
    qtb[u * 8 + j] = pk1(s);
}

// ---- A: phase-separated streaming row pass ----
__global__ __launch_bounds__(512, 4) void pgc_rows(
    const float* __restrict__ act,
    const float* __restrict__ ema,
    const float* __restrict__ plab,
    const float* __restrict__ mask,
    unsigned long long* __restrict__ afb,   // [row*16 + u]
    float4* __restrict__ rowmeta,           // {def2, mk, lb, 0}
    int B)
{
    __shared__ float ps[TR * 32];           // 8 KB: act partial dots
    __shared__ float pe[TR * 32];           // 8 KB: ema partial dots
    __shared__ float pd[TR * 32];           // 8 KB: cross dots
    __shared__ float s_gs[TR];

    const int tid = threadIdx.x;
    const long R0  = (long)blockIdx.x * TR;
    const long fbase = R0 * 32;             // tile base in float4 units

    // ---- Phase A: copy-like streaming, zero cross-lane ----
    const float4* a4 = (const float4*)act;
    const float4* e4 = (const float4*)ema;
    const long fmax = (long)B * 32;
    #pragma unroll
    for (int i = 0; i < 4; ++i) {
        long f = fbase + i * 512 + tid;
        long fc = f < fmax ? f : fmax - 1;
        float4 a = a4[fc];
        float4 e = e4[fc];
        int row  = i * 16 + (tid >> 5);     // (i*512+tid)>>5
        int slot = tid & 31;
        ps[row * 32 + slot] = a.x*a.x + a.y*a.y + a.z*a.z + a.w*a.w;
        pe[row * 32 + slot] = e.x*e.x + e.y*e.y + e.z*e.z + e.w*e.w;
        pd[row * 32 + slot] = a.x*e.x + a.y*e.y + a.z*e.z + a.w*e.w;
    }
    __syncthreads();

    // ---- Phase B: per-row reduce + meta (64 threads) ----
    if (tid < TR) {
        float ssa = 0.f, sse = 0.f, dae = 0.f;
        #pragma unroll
        for (int s = 0; s < 32; ++s) {
            ssa += ps[tid * 32 + s];
            sse += pe[tid * 32 + s];
            dae += pd[tid * 32 + s];
        }
        const float inva = 1.0f / fmaxf(sqrtf(ssa), 1e-12f);
        const float inve = 1.0f / fmaxf(sqrtf(sse), 1e-12f);
        s_gs[tid] = 2.0f * inva;            // fold 1/T + norm into A

        const long row = R0 + tid;
        const bool valid = row < (long)B;
        const long gr = valid ? row : (long)B - 1;
        float mk = valid ? mask[gr] : 0.f;
        const float* pp = plab + gr * 3;
        float p0 = pp[0], p1 = pp[1], p2 = pp[2];
        int lb = 0; float bst = p0;
        if (p1 > bst) { bst = p1; lb = 1; }          // first-max = argmax
        if (p2 > bst) { lb = 2; }
        if (valid)
            rowmeta[row] = make_float4(2.0f * dae * inva * inve,
                                       mk, (float)lb, 0.f);
    }
    __syncthreads();

    // ---- Phase C: fragment pack from L2-hot act, coalesced stores ----
    #pragma unroll
    for (int rep = 0; rep < 2; ++rep) {
        const int u   = tid & 15;
        const int row = (tid >> 4) + rep * 32;       // 0..63
        const long grow = R0 + row;
        const bool valid = grow < (long)B;
        const long gr = valid ? grow : (long)B - 1;
        const float4* r4 = a4 + gr * 32;
        float4 x = r4[2 * u], y = r4[2 * u + 1];     // L2-hot re-read
        const float gs = s_gs[row];
        float4 sx = make_float4(gs*x.x, gs*x.y, gs*x.z, gs*x.w);
        float4 sy = make_float4(gs*y.x, gs*y.y, gs*y.z, gs*y.w);
        unsigned long long frag =
            ((unsigned long long)pk4(sy) << 32) | (unsigned long long)pk4(sx);
        if (valid)
            afb[grow * 16 + u] = frag;               // coalesced 8B/thread
    }
}

// ---- B: qt-in-LDS MFMA pass (R16 proven loop) ----
__global__ __launch_bounds__(512, 4) void pgc_mm(
    const unsigned long long* __restrict__ afb,
    const float4* __restrict__ rowmeta,
    const unsigned long long* __restrict__ qt,
    float* __restrict__ partial,
    int B)
{
    __shared__ unsigned long long qt_lds[6144];      // 49152 B
    __shared__ float s_red[8];

    const int tid = threadIdx.x;
    const int w   = tid >> 6;      // 0..7
    const int l   = tid & 63;
    const int lr  = l & 15;
    const int seg = l >> 4;
    const long rowbase = (long)blockIdx.x * 128 + w * 16;

    // ---- stage qt -> LDS: 6 glds/thread, fire-and-forget ----
    #pragma unroll
    for (int i = 0; i < 6; ++i) {
        glds16((const char*)qt + i * 8192 + w * 1024 + l * 16,
               (char*)qt_lds + i * 8192 + w * 1024);
    }

    // ---- tiny global reads: af fragments (32B) + own-row meta (16B) ----
    long grow = rowbase + lr;
    const bool valid = grow < (long)B;
    const long gr = valid ? grow : (long)B - 1;

    const unsigned long long* ap = afb + gr * 16 + seg * 4;
    long af[4];
    af[0] = (long)ap[0]; af[1] = (long)ap[1];
    af[2] = (long)ap[2]; af[3] = (long)ap[3];
    float4 meta = rowmeta[gr];
    const float def2 = meta.x;
    const float mk   = valid ? meta.y : 0.f;
    const int   lb   = (int)meta.z;

    __syncthreads();   // drains glds -> qt_lds ready

    // ---- 24-tile fp8 MFMA loop (R16 form) ----
    float S1[4] = {0.f, 0.f, 0.f, 0.f};
    f32x4 a23 = {0.f, 0.f, 0.f, 0.f};
    #pragma unroll
    for (int nt = 0; nt < 24; ++nt) {
        long b0 = (long)qt_lds[nt * 256 +       l];
        long b1 = (long)qt_lds[nt * 256 +  64 + l];
        long b2 = (long)qt_lds[nt * 256 + 128 + l];
        long b3 = (long)qt_lds[nt * 256 + 192 + l];
        f32x4 acc = {0.f, 0.f, 0.f, 0.f};
        acc = __builtin_amdgcn_mfma_f32_16x16x32_fp8_fp8(af[0], b0, acc, 0, 0, 0);
        acc = __builtin_amdgcn_mfma_f32_16x16x32_fp8_fp8(af[1], b1, acc, 0, 0, 0);
        acc = __builtin_amdgcn_mfma_f32_16x16x32_fp8_fp8(af[2], b2, acc, 0, 0, 0);
        acc = __builtin_amdgcn_mfma_f32_16x16x32_fp8_fp8(af[3], b3, acc, 0, 0, 0);
        if (nt < 23) {
            #pragma unroll
            for (int r = 0; r < 4; ++r)
                S1[r] += __expf(acc[r]);
        } else {
            a23 = acc;                 // lanes 7..9 hold class S2; lr<7 real
            if (lr < 7) {
                #pragma unroll
                for (int r = 0; r < 4; ++r)
                    S1[r] += __expf(acc[r]);
            }
        }
    }

    // ---- reduce S1 over the 16 column lanes ----
    #pragma unroll
    for (int r = 0; r < 4; ++r) {
        S1[r] += __shfl_xor(S1[r], 1);
        S1[r] += __shfl_xor(S1[r], 2);
        S1[r] += __shfl_xor(S1[r], 4);
        S1[r] += __shfl_xor(S1[r], 8);
    }

    // ---- epilogue: S2 via variable-lane shuffle from tile-23 acc ----
    float c = 0.f;
    #pragma unroll
    for (int r = 0; r < 4; ++r) {
        const int m   = seg * 4 + r;
        const int lbm = __shfl(lb, m);
        const float S2 = __shfl(a23[r], (l & 48) + 7 + lbm);
        const float d2 = __shfl(def2, m);
        const float mm = __shfl(mk, m);
        const float denom = __expf(d2) + S1[r];
        const float per = __logf(denom) - (S2 + d2) * INV126;
        if (lr == 0) c += mm * per;
    }
    c += __shfl_xor(c, 16);
    c += __shfl_xor(c, 32);
    if (l == 0) s_red[w] = c;
    __syncthreads();
    if (w == 0) {
        float v = (l < 8) ? s_red[l] : 0.f;
        v += __shfl_xor(v, 1); v += __shfl_xor(v, 2); v += __shfl_xor(v, 4);
        if (l == 0) partial[blockIdx.x] = v;
    }
}

// ---- finish: deterministic tree reduce ----
__global__ void pgc_finish(const float* __restrict__ partial,
                           float* __restrict__ out, int n, float invB)
{
    __shared__ float r[4];
    const int tid = threadIdx.x;
    float s = 0.f;
    for (int i = tid; i < n; i += 256) s += partial[i];
    s += __shfl_xor(s, 1);  s += __shfl_xor(s, 2);
    s += __shfl_xor(s, 4);  s += __shfl_xor(s, 8);
    s += __shfl_xor(s, 16); s += __shfl_xor(s, 32);
    if ((tid & 63) == 0) r[tid >> 6] = s;
    __syncthreads();
    if (tid == 0) out[0] = (r[0] + r[1] + r[2] + r[3]) * invB;
}

extern "C" void kernel_launch(void* const* d_in, const int* in_sizes, int n_in,
                              void* d_out, int out_size, void* d_ws, size_t ws_size,
                              hipStream_t stream)
{
    const float* act   = (const float*)d_in[0];
    const float* ema   = (const float*)d_in[1];
    const float* plab  = (const float*)d_in[2];
    const float* mask  = (const float*)d_in[3];
    const float* queue = (const float*)d_in[4];
    float* out = (float*)d_out;

    const int B = in_sizes[0] / D;
    const long Brnd = ((long)B + 255) & ~255L;

    // ws layout: qt 48KB | partial 16KB | rowmeta 16B*Brnd | afb 128B*Brnd
    unsigned long long* qt = (unsigned long long*)d_ws;
    float* partial = (float*)((char*)d_ws + QT_BYTES);
    float4* rowmeta = (float4*)((char*)d_ws + QT_BYTES + 16384);
    unsigned long long* afb =
        (unsigned long long*)((char*)d_ws + QT_BYTES + 16384 + Brnd * 16);

    pgc_prep<<<24, 256, 0, stream>>>(queue, qt);
    pgc_prep_qsum<<<3, 128, 0, stream>>>(queue, (unsigned char*)d_ws);

    const int gridA = (B + TR - 1) / TR;     // 2048
    pgc_rows<<<gridA, 512, 0, stream>>>(act, ema, plab, mask, afb, rowmeta, B);

    const int gridB = (B + 127) / 128;       // 1024
    pgc_mm<<<gridB, 512, 0, stream>>>(afb, rowmeta, qt, partial, B);

    pgc_finish<<<1, 256, 0, stream>>>(partial, out, gridB, 1.0f / (float)B);
}

// Round 24
// 57.892 us; speedup vs baseline: 1.1303x; 1.1303x over previous
//
#include <hip/hip_runtime.h>
#include <math.h>

// PseudoGroupContrast — R16 base (session best, 46.6 µs) + launch-overhead
// trims. R16 = qt-in-LDS + forced-wide load batch (sched_barrier) fused
// kernel. Deltas vs R16: (1) finish kernel folded into main via one
// atomicAdd/block (removes 1 launch + 1 graph gap); (2) prepQ serial chain
// halved (2x128-row split). Everything else byte-identical.
//
//   prep:   queue fp32 -> fp8 e4m3, MFMA-fragment-tiled, in d_ws (48 KB).
//   prepQ:  per-class queue sums (fp8) into pad rows 375..377 (tile 23).
//   main:   grid B/128, block 512 (8 waves), LDS 48 KB, lb(512,4).
//           - 6 glds/thread stage qt -> LDS (fire-and-forget)
//           - act(8)+ema(8)+mask/plab issued wide, sched_barrier, consume
//           - one __syncthreads (drains glds) -> qt ready
//           - 24-tile loop: 4 ds_read_b64 + 4 fp8 MFMA + 4 __expf;
//             tile 23: lr<7 -> S1, lanes 7..9 carry S2 per class
//           per = log(exp(def2)+S1) - (S2+def2)/126, def2 = 2*f_hat.ef_hat
//           block partial -> atomicAdd(out).

#define D       128
#define NQ      375
#define QS      125
#define INV126  (1.0f/126.0f)
#define QT_BYTES 49152

typedef __attribute__((ext_vector_type(4))) float f32x4;

#if defined(__has_builtin)
#if __has_builtin(__builtin_amdgcn_cvt_pk_fp8_f32)
#define HAVE_CVT_FP8 1
#endif
#endif

#ifndef HAVE_CVT_FP8
static __device__ __forceinline__ unsigned f2e4m3_sw(float x) {
    unsigned u = __float_as_uint(x);
    unsigned s = (u >> 24) & 0x80;
    int e = (int)((u >> 23) & 0xFF);
    unsigned m = u & 0x7FFFFF;
    if (e == 0) return s;
    int te = e - 120;
    unsigned val;
    if (te >= 1) {
        unsigned keep = m >> 20;
        unsigned rest = m & 0xFFFFF;
        keep += (rest > 0x80000) || (rest == 0x80000 && (keep & 1));
        if (keep == 8) { keep = 0; te += 1; }
        val = (te >= 16) ? 0x7E : ((unsigned)(te << 3) | keep);
    } else {
        unsigned full = m | 0x800000;
        int sh = 21 - te;
        if (sh > 31) val = 0;
        else {
            unsigned keep = full >> sh;
            unsigned rem = full & ((1u << sh) - 1);
            unsigned half = 1u << (sh - 1);
            keep += (rem > half) || (rem == half && (keep & 1));
            val = keep;
        }
    }
    return s | val;
}
#endif

static __device__ __forceinline__ unsigned pk4(float4 v) {
#ifdef HAVE_CVT_FP8
    int r = __builtin_amdgcn_cvt_pk_fp8_f32(v.x, v.y, 0, false);
    r = __builtin_amdgcn_cvt_pk_fp8_f32(v.z, v.w, r, true);
    return (unsigned)r;
#else
    return f2e4m3_sw(v.x) | (f2e4m3_sw(v.y) << 8)
         | (f2e4m3_sw(v.z) << 16) | (f2e4m3_sw(v.w) << 24);
#endif
}

static __device__ __forceinline__ unsigned char pk1(float x) {
#ifdef HAVE_CVT_FP8
    return (unsigned char)(__builtin_amdgcn_cvt_pk_fp8_f32(x, x, 0, false) & 0xff);
#else
    return (unsigned char)f2e4m3_sw(x);
#endif
}

static __device__ __forceinline__ long pk8(float gs, float4 a, float4 b) {
    float4 sa = make_float4(gs * a.x, gs * a.y, gs * a.z, gs * a.w);
    float4 sb = make_float4(gs * b.x, gs * b.y, gs * b.z, gs * b.w);
    unsigned lo = pk4(sa), hi = pk4(sb);
    return (long)(((unsigned long)hi << 32) | (unsigned long)lo);
}

static __device__ __forceinline__ void glds16(const void* g, void* l) {
    __builtin_amdgcn_global_load_lds(
        (const __attribute__((address_space(1))) void*)g,
        (__attribute__((address_space(3))) void*)l, 16, 0, 0);
}

// ---- prep: queue -> fp8, fragment-tiled (rows >= 375 zeroed) ----
__global__ void pgc_prep(const float* __restrict__ queue,
                         unsigned long long* __restrict__ qt)
{
    int u = blockIdx.x * 256 + threadIdx.x;      // 0..6143
    if (u >= 6144) return;
    int l = u & 63, ks = (u >> 6) & 3, nt = u >> 8;
    int row = nt * 16 + (l & 15);
    int k0 = (l >> 4) * 32 + ks * 8;
    float4 a = make_float4(0.f, 0.f, 0.f, 0.f);
    float4 b = make_float4(0.f, 0.f, 0.f, 0.f);
    if (row < NQ) {
        const float* p = queue + row * D + k0;
        a = *(const float4*)p;
        b = *(const float4*)(p + 4);
    }
    unsigned lo = pk4(a), hi = pk4(b);
    qt[u] = ((unsigned long long)hi << 32) | (unsigned long long)lo;
}

// ---- prepQ: class sums into pad rows 375..377 (2-half split) ----
__global__ void pgc_prep_qsum(const float* __restrict__ queue,
                              unsigned char* __restrict__ qtb)
{
    __shared__ float half_[128];
    int c = blockIdx.x;              // 0..2
    int t = threadIdx.x;             // 0..255
    int d = t & 127;
    int h = t >> 7;                  // 0 or 1
    int r0 = h ? 63 : 0, r1 = h ? QS : 63;
    float s = 0.f;
    const float* p = queue + (long)c * QS * D + d;
    for (int r = r0; r < r1; ++r) s += p[r * D];
    if (h) half_[d] = s;
    __syncthreads();
    if (!h) {
        s += half_[d];
        int lg = d >> 5, ks = (d >> 3) & 3, j = d & 7;
        int u = 23 * 256 + ks * 64 + lg * 16 + 7 + c;    // tile 23, lr = 7+c
        qtb[u * 8 + j] = pk1(s);
    }
}

// ---- main ----
__global__ __launch_bounds__(512, 4) void pgc_main(
    const float* __restrict__ act,
    const float* __restrict__ ema,
    const float* __restrict__ plab,
    const float* __restrict__ mask,
    const unsigned long long* __restrict__ qt,
    float* __restrict__ out,
    int B, float invB)
{
    __shared__ unsigned long long qt_lds[6144];      // 49152 B
    __shared__ float s_red[8];

    const int tid = threadIdx.x;
    const int w   = tid >> 6;      // 0..7
    const int l   = tid & 63;
    const int lr  = l & 15;        // own sample row / C col
    const int seg = l >> 4;        // k-segment / C row group
    const long rowbase = (long)blockIdx.x * 128 + w * 16;

    // ---- 1) stage qt -> LDS: 6 glds/thread, fire-and-forget ----
    #pragma unroll
    for (int i = 0; i < 6; ++i) {
        glds16((const char*)qt + i * 8192 + w * 1024 + l * 16,
               (char*)qt_lds + i * 8192 + w * 1024);
    }

    // ---- 2) issue the ENTIRE sample load batch ----
    long grow = rowbase + lr;
    const bool valid = grow < (long)B;
    const long gr = valid ? grow : (long)B - 1;

    const float4* ap = (const float4*)(act + gr * D) + seg * 8;
    const float4* ep = (const float4*)(ema + gr * D) + seg * 8;

    float4 av[8], ev[8];
    #pragma unroll
    for (int i = 0; i < 8; ++i) av[i] = ap[i];
    #pragma unroll
    for (int i = 0; i < 8; ++i) ev[i] = ep[i];

    float mk_raw = mask[gr];
    const float* pp = plab + gr * 3;
    float p0 = pp[0], p1 = pp[1], p2 = pp[2];

    __builtin_amdgcn_sched_barrier(0);   // loads stay issued ABOVE; consume below

    // ---- 3) consume act (partial vmcnt; ema/mask still in flight) ----
    float ssa = 0.f;
    #pragma unroll
    for (int i = 0; i < 8; ++i)
        ssa += av[i].x*av[i].x + av[i].y*av[i].y + av[i].z*av[i].z + av[i].w*av[i].w;
    ssa += __shfl_xor(ssa, 16); ssa += __shfl_xor(ssa, 32);
    const float inva = 1.0f / fmaxf(sqrtf(ssa), 1e-12f);
    const float gs   = 2.0f * inva;                  // fold 1/T + norm into A

    long af[4];
    #pragma unroll
    for (int ks = 0; ks < 4; ++ks)                   // k = seg*32 + ks*8 ..
        af[ks] = pk8(gs, av[2 * ks], av[2 * ks + 1]);

    // ---- 4) consume ema ----
    float sse = 0.f, dae = 0.f;
    #pragma unroll
    for (int i = 0; i < 8; ++i) {
        sse += ev[i].x*ev[i].x + ev[i].y*ev[i].y + ev[i].z*ev[i].z + ev[i].w*ev[i].w;
        dae += av[i].x*ev[i].x + av[i].y*ev[i].y + av[i].z*ev[i].z + av[i].w*ev[i].w;
    }
    sse += __shfl_xor(sse, 16); sse += __shfl_xor(sse, 32);
    dae += __shfl_xor(dae, 16); dae += __shfl_xor(dae, 32);
    const float inve = 1.0f / fmaxf(sqrtf(sse), 1e-12f);
    const float def2 = 2.0f * dae * inva * inve;

    // ---- 5) own-row scalars ----
    float mk = valid ? mk_raw : 0.f;
    int lb = 0; float bst = p0;
    if (p1 > bst) { bst = p1; lb = 1; }              // first-max = argmax
    if (p2 > bst) { lb = 2; }

    __syncthreads();   // drains glds -> qt_lds ready

    // ---- 6) 24-tile fp8 MFMA loop; B from LDS (2 lanes/bank = free) ----
    float S1[4] = {0.f, 0.f, 0.f, 0.f};
    f32x4 a23 = {0.f, 0.f, 0.f, 0.f};
    #pragma unroll
    for (int nt = 0; nt < 24; ++nt) {
        long b0 = (long)qt_lds[nt * 256 +       l];
        long b1 = (long)qt_lds[nt * 256 +  64 + l];
        long b2 = (long)qt_lds[nt * 256 + 128 + l];
        long b3 = (long)qt_lds[nt * 256 + 192 + l];
        f32x4 acc = {0.f, 0.f, 0.f, 0.f};
        acc = __builtin_amdgcn_mfma_f32_16x16x32_fp8_fp8(af[0], b0, acc, 0, 0, 0);
        acc = __builtin_amdgcn_mfma_f32_16x16x32_fp8_fp8(af[1], b1, acc, 0, 0, 0);
        acc = __builtin_amdgcn_mfma_f32_16x16x32_fp8_fp8(af[2], b2, acc, 0, 0, 0);
        acc = __builtin_amdgcn_mfma_f32_16x16x32_fp8_fp8(af[3], b3, acc, 0, 0, 0);
        if (nt < 23) {
            #pragma unroll
            for (int r = 0; r < 4; ++r)
                S1[r] += __expf(acc[r]);
        } else {
            a23 = acc;                 // lanes 7..9 hold class S2; lr<7 real
            if (lr < 7) {
                #pragma unroll
                for (int r = 0; r < 4; ++r)
                    S1[r] += __expf(acc[r]);
            }
        }
    }

    // ---- 7) reduce S1 over the 16 column lanes ----
    #pragma unroll
    for (int r = 0; r < 4; ++r) {
        S1[r] += __shfl_xor(S1[r], 1);
        S1[r] += __shfl_xor(S1[r], 2);
        S1[r] += __shfl_xor(S1[r], 4);
        S1[r] += __shfl_xor(S1[r], 8);
    }

    // ---- 8) epilogue: S2 via variable-lane shuffle from tile-23 acc ----
    float c = 0.f;
    #pragma unroll
    for (int r = 0; r < 4; ++r) {
        const int m   = seg * 4 + r;                 // output row index in wave
        const int lbm = __shfl(lb, m);               // label of row m
        const float S2 = __shfl(a23[r], (l & 48) + 7 + lbm);  // C[m][375+lbm]
        const float d2 = __shfl(def2, m);
        const float mm = __shfl(mk, m);
        const float denom = __expf(d2) + S1[r];      // exactly 375 real cols
        const float per = __logf(denom) - (S2 + d2) * INV126;
        if (lr == 0) c += mm * per;
    }
    c += __shfl_xor(c, 16);
    c += __shfl_xor(c, 32);
    if (l == 0) s_red[w] = c;
    __syncthreads();
    if (w == 0) {
        float v = (l < 8) ? s_red[l] : 0.f;
        v += __shfl_xor(v, 1); v += __shfl_xor(v, 2); v += __shfl_xor(v, 4);
        if (l == 0) atomicAdd(out, v * invB);        // finish folded in
    }
}

extern "C" void kernel_launch(void* const* d_in, const int* in_sizes, int n_in,
                              void* d_out, int out_size, void* d_ws, size_t ws_size,
                              hipStream_t stream)
{
    const float* act   = (const float*)d_in[0];
    const float* ema   = (const float*)d_in[1];
    const float* plab  = (const float*)d_in[2];
    const float* mask  = (const float*)d_in[3];
    const float* queue = (const float*)d_in[4];
    float* out = (float*)d_out;

    const int B = in_sizes[0] / D;

    unsigned long long* qt = (unsigned long long*)d_ws;

    hipMemsetAsync(out, 0, sizeof(float), stream);

    pgc_prep<<<24, 256, 0, stream>>>(queue, qt);
    pgc_prep_qsum<<<3, 256, 0, stream>>>(queue, (unsigned char*)d_ws);

    const int grid = (B + 127) / 128;        // 1024 for B=131072
    pgc_main<<<grid, 512, 0, stream>>>(act, ema, plab, mask, qt, out,
                                       B, 1.0f / (float)B);
}